// Round 1
// baseline (1178.999 us; speedup 1.0000x reference)
//
#include <hip/hip_runtime.h>
#include <cstdint>
#include <cstddef>

#define B_ 16
#define E_ 1024
#define N_ 1024
#define H_ 128
#define CAP 256   // max nonzeros per row/col; Bernoulli(0.1,1024): mean 102, std 9.6 -> P(>256) ~ 0

typedef unsigned short u16;

__device__ __forceinline__ float wave_sum64(float v) {
    v += __shfl_xor(v, 32);
    v += __shfl_xor(v, 16);
    v += __shfl_xor(v, 8);
    v += __shfl_xor(v, 4);
    v += __shfl_xor(v, 2);
    v += __shfl_xor(v, 1);
    return v;
}

__device__ __forceinline__ float wave_max64(float v) {
    v = fmaxf(v, __shfl_xor(v, 32));
    v = fmaxf(v, __shfl_xor(v, 16));
    v = fmaxf(v, __shfl_xor(v, 8));
    v = fmaxf(v, __shfl_xor(v, 4));
    v = fmaxf(v, __shfl_xor(v, 2));
    v = fmaxf(v, __shfl_xor(v, 1));
    return v;
}

// Build row nonzero lists: one block per (b,e). Coalesced reads, ordered
// (ascending n) compaction via ballot + cross-wave prefix. Deterministic.
__global__ void build_rows(const float* __restrict__ adj,
                           u16* __restrict__ idx, int* __restrict__ cnt_out) {
    int be = blockIdx.x;                      // b*E + e
    const float* row = adj + (size_t)be * N_;
    __shared__ int wcnt[4];
    __shared__ int base;
    int tid = threadIdx.x, lane = tid & 63, wv = tid >> 6;
    if (tid == 0) base = 0;
    __syncthreads();
    for (int c0 = 0; c0 < N_; c0 += 256) {
        float v = row[c0 + tid];
        unsigned long long m = __ballot(v != 0.0f);
        if (lane == 0) wcnt[wv] = __popcll(m);
        __syncthreads();
        int pos = base;
        for (int w = 0; w < wv; ++w) pos += wcnt[w];
        pos += __popcll(m & ((1ull << lane) - 1ull));
        if (v != 0.0f && pos < CAP)
            idx[(size_t)be * CAP + pos] = (u16)(c0 + tid);
        __syncthreads();
        if (tid == 0) base += wcnt[0] + wcnt[1] + wcnt[2] + wcnt[3];
        __syncthreads();
    }
    if (tid == 0) cnt_out[be] = base < CAP ? base : CAP;
}

// Build column nonzero lists: thread-per-column so adj reads are coalesced
// (threads n..n+255 read consecutive addresses per e). Each thread appends
// e's to its own list in ascending order. Grid: B * (N/256) blocks.
__global__ void build_cols(const float* __restrict__ adj,
                           u16* __restrict__ idx, int* __restrict__ cnt_out) {
    int blk = blockIdx.x;                 // b*(N/256) + chunk
    int b = blk >> 2;
    int n = ((blk & 3) << 8) + threadIdx.x;
    const float* base = adj + (size_t)b * E_ * N_ + n;
    size_t bn = (size_t)b * N_ + n;
    u16* lst = idx + bn * CAP;
    int c = 0;
#pragma unroll 4
    for (int e = 0; e < E_; ++e) {
        float v = base[(size_t)e * N_];
        if (v != 0.0f && c < CAP) lst[c++] = (u16)e;
    }
    cnt_out[bn] = c;
}

// edge_init[b,e,d] = mean over incident nodes of nodes[b,n,d]
__global__ void edge_init(const float* __restrict__ nodes,
                          const u16* __restrict__ ridx, const int* __restrict__ rcnt,
                          float* __restrict__ edge) {
    int be = blockIdx.x;
    int b = be >> 10;
    int tid = threadIdx.x;                // 128 threads
    __shared__ u16 sidx[CAP];
    int cnt = rcnt[be];
    for (int i = tid; i < cnt; i += 128) sidx[i] = ridx[(size_t)be * CAP + i];
    __syncthreads();
    const float* nb = nodes + (size_t)b * N_ * H_;
    float acc = 0.f;
    for (int i = 0; i < cnt; ++i) acc += nb[(size_t)sidx[i] * H_ + tid];
    float inv = 1.0f / (float)(cnt > 0 ? cnt : 1);
    edge[(size_t)be * H_ + tid] = acc * inv;
}

// Generic masked-softmax attention over a nonzero list.
//   q = qsrc[row] * w[:H];  score_j = leaky_relu(dot(q, kv[list[j]]) + w[H])
//   out[row] = sum_j softmax(score)_j * kv[list[j]]
// SAFE for qsrc == out: block reads only its own row before writing it.
__global__ void attn_gather(const float* __restrict__ qsrc,   // (B,1024,H)
                            const float* __restrict__ kv,     // (B,1024,H)
                            const float* __restrict__ w,      // (H+1)
                            const u16* __restrict__ lidx, const int* __restrict__ lcnt,
                            float* __restrict__ out) {        // (B,1024,H)
    int br = blockIdx.x;
    int b = br >> 10;
    int tid = threadIdx.x, lane = tid & 63, wv = tid >> 6;   // 256 threads
    __shared__ float q[H_];
    __shared__ u16 sidx[CAP];
    __shared__ float sc[CAP];
    __shared__ float rtmp[4];
    __shared__ float part[256];
    int cnt = lcnt[br];
    for (int i = tid; i < cnt; i += 256) sidx[i] = lidx[(size_t)br * CAP + i];
    if (tid < H_) q[tid] = qsrc[(size_t)br * H_ + tid] * w[tid];
    __syncthreads();
    float wb = w[H_];
    const float* kvb = kv + (size_t)b * 1024 * H_;
    // scores: one wave per list entry
    for (int i = wv; i < cnt; i += 4) {
        const float* krow = kvb + (size_t)sidx[i] * H_;
        float p = q[lane] * krow[lane] + q[lane + 64] * krow[lane + 64];
        p = wave_sum64(p);
        if (lane == 0) {
            p += wb;
            sc[i] = p >= 0.f ? p : 0.2f * p;   // LeakyReLU(0.2)
        }
    }
    __syncthreads();
    // softmax over sc[0..cnt)
    float v = (tid < cnt) ? sc[tid] : -1e30f;
    v = wave_max64(v);
    if (lane == 0) rtmp[wv] = v;
    __syncthreads();
    float m = fmaxf(fmaxf(rtmp[0], rtmp[1]), fmaxf(rtmp[2], rtmp[3]));
    float ee = (tid < cnt) ? __expf(sc[tid] - m) : 0.f;
    float s = wave_sum64(ee);
    __syncthreads();                 // all reads of rtmp (max) done before reuse
    if (lane == 0) rtmp[wv] = s;
    if (tid < cnt) sc[tid] = ee;     // owner-only rewrite
    __syncthreads();
    float denom = rtmp[0] + rtmp[1] + rtmp[2] + rtmp[3];
    float rden = denom > 0.f ? 1.0f / denom : 0.f;
    // aggregate: two list-halves in parallel, combine in LDS
    int d = tid & 127, h = tid >> 7;
    float acc = 0.f;
    for (int i = h; i < cnt; i += 2)
        acc += sc[i] * kvb[(size_t)sidx[i] * H_ + d];
    part[tid] = acc;
    __syncthreads();
    if (tid < 128)
        out[(size_t)br * H_ + tid] = (part[tid] + part[tid + 128]) * rden;
}

extern "C" void kernel_launch(void* const* d_in, const int* in_sizes, int n_in,
                              void* d_out, int out_size, void* d_ws, size_t ws_size,
                              hipStream_t stream) {
    const float* nodes_in = (const float*)d_in[0];   // (B,N,H) f32
    const float* adj      = (const float*)d_in[1];   // (B,E,N) f32, binary
    const float* w1       = (const float*)d_in[2];   // (H+1)
    const float* w2       = (const float*)d_in[3];   // (H+1)

    char* ws = (char*)d_ws;
    size_t off = 0;
    u16* row_idx = (u16*)(ws + off); off += (size_t)B_ * E_ * CAP * sizeof(u16);
    u16* col_idx = (u16*)(ws + off); off += (size_t)B_ * N_ * CAP * sizeof(u16);
    int* row_cnt = (int*)(ws + off); off += (size_t)B_ * E_ * sizeof(int);
    int* col_cnt = (int*)(ws + off); off += (size_t)B_ * N_ * sizeof(int);

    float* out_nodes = (float*)d_out;                       // (B,N,H)
    float* out_edge  = out_nodes + (size_t)B_ * N_ * H_;    // (B,E,H)

    build_rows<<<dim3(B_ * E_), dim3(256), 0, stream>>>(adj, row_idx, row_cnt);
    build_cols<<<dim3(B_ * (N_ / 256)), dim3(256), 0, stream>>>(adj, col_idx, col_cnt);
    edge_init<<<dim3(B_ * E_), dim3(128), 0, stream>>>(nodes_in, row_idx, row_cnt, out_edge);

    const float* ncur = nodes_in;
    for (int s = 0; s < 2; ++s) {
        // edge = alpha-attention(edge, nodes); in-place in out_edge (row-local alias)
        attn_gather<<<dim3(B_ * E_), dim3(256), 0, stream>>>(
            out_edge, ncur, w1, row_idx, row_cnt, out_edge);
        // nodes = beta-attention(nodes, edge); lands in out_nodes (row-local alias on step 1)
        attn_gather<<<dim3(B_ * N_), dim3(256), 0, stream>>>(
            ncur, out_edge, w2, col_idx, col_cnt, out_nodes);
        ncur = out_nodes;
    }
}

// Round 2
// 786.631 us; speedup vs baseline: 1.4988x; 1.4988x over previous
//
#include <hip/hip_runtime.h>
#include <cstdint>
#include <cstddef>

#define B_ 16
#define E_ 1024
#define N_ 1024
#define H_ 128
#define CAP 256   // max nonzeros per row/col; Bernoulli(0.1,1024): mean 102, std 9.6
#define NC 16     // e-chunks for column build
#define EC 64     // E_/NC

typedef unsigned short u16;

__device__ __forceinline__ float wave_sum64(float v) {
    v += __shfl_xor(v, 32);
    v += __shfl_xor(v, 16);
    v += __shfl_xor(v, 8);
    v += __shfl_xor(v, 4);
    v += __shfl_xor(v, 2);
    v += __shfl_xor(v, 1);
    return v;
}

__device__ __forceinline__ float wave_max64(float v) {
    v = fmaxf(v, __shfl_xor(v, 32));
    v = fmaxf(v, __shfl_xor(v, 16));
    v = fmaxf(v, __shfl_xor(v, 8));
    v = fmaxf(v, __shfl_xor(v, 4));
    v = fmaxf(v, __shfl_xor(v, 2));
    v = fmaxf(v, __shfl_xor(v, 1));
    return v;
}

// Row nonzero lists: one block per (b,e). Coalesced, ordered (ascending n).
__global__ void build_rows(const float* __restrict__ adj,
                           u16* __restrict__ idx, int* __restrict__ cnt_out) {
    int be = blockIdx.x;                      // b*E + e
    const float* row = adj + (size_t)be * N_;
    __shared__ int wcnt[4];
    __shared__ int base;
    int tid = threadIdx.x, lane = tid & 63, wv = tid >> 6;
    if (tid == 0) base = 0;
    __syncthreads();
    for (int c0 = 0; c0 < N_; c0 += 256) {
        float v = row[c0 + tid];
        unsigned long long m = __ballot(v != 0.0f);
        if (lane == 0) wcnt[wv] = __popcll(m);
        __syncthreads();
        int pos = base;
        for (int w = 0; w < wv; ++w) pos += wcnt[w];
        pos += __popcll(m & ((1ull << lane) - 1ull));
        if (v != 0.0f && pos < CAP)
            idx[(size_t)be * CAP + pos] = (u16)(c0 + tid);
        __syncthreads();
        if (tid == 0) base += wcnt[0] + wcnt[1] + wcnt[2] + wcnt[3];
        __syncthreads();
    }
    if (tid == 0) cnt_out[be] = base < CAP ? base : CAP;
}

// --- Column lists, 3-phase parallel, deterministic (ascending e) ---
// Phase A: per-(b, chunk, n) counts. Grid: 16*NC*4 blocks, 256 thr.
__global__ void col_count(const float* __restrict__ adj, int* __restrict__ cnt_chunk) {
    int blk = blockIdx.x;
    int ng = blk & 3;                 // n-group
    int c  = (blk >> 2) & (NC - 1);   // e-chunk
    int b  = blk >> 6;
    int n = (ng << 8) + threadIdx.x;
    const float* base = adj + ((size_t)(b * E_ + c * EC)) * N_ + n;
    int cc = 0;
#pragma unroll 8
    for (int e = 0; e < EC; ++e)
        cc += (base[(size_t)e * N_] != 0.0f);
    cnt_chunk[(size_t)(b * NC + c) * N_ + n] = cc;
}

// Phase B: exclusive prefix over chunks per (b,n); total count (capped).
__global__ void col_prefix(const int* __restrict__ cnt_chunk,
                           int* __restrict__ off_chunk, int* __restrict__ cnt_out) {
    int idx = blockIdx.x * 256 + threadIdx.x;   // b*N + n
    int b = idx >> 10, n = idx & 1023;
    int run = 0;
    for (int c = 0; c < NC; ++c) {
        size_t p = (size_t)(b * NC + c) * N_ + n;
        off_chunk[p] = run;
        run += cnt_chunk[p];
    }
    cnt_out[idx] = run < CAP ? run : CAP;
}

// Phase C: placement at precomputed offsets. Same grid as A.
__global__ void col_place(const float* __restrict__ adj,
                          const int* __restrict__ off_chunk, u16* __restrict__ idx) {
    int blk = blockIdx.x;
    int ng = blk & 3;
    int c  = (blk >> 2) & (NC - 1);
    int b  = blk >> 6;
    int n = (ng << 8) + threadIdx.x;
    const float* base = adj + ((size_t)(b * E_ + c * EC)) * N_ + n;
    int pos = off_chunk[(size_t)(b * NC + c) * N_ + n];
    u16* lst = idx + ((size_t)b * N_ + n) * CAP;
    for (int e = 0; e < EC; ++e) {
        if (base[(size_t)e * N_] != 0.0f) {
            if (pos < CAP) lst[pos] = (u16)(c * EC + e);
            ++pos;
        }
    }
}

// edge_init[b,e,:] = mean of incident node rows. 256 thr, float2, 4-way.
__global__ void edge_init(const float* __restrict__ nodes,
                          const u16* __restrict__ ridx, const int* __restrict__ rcnt,
                          float* __restrict__ edge) {
    int be = blockIdx.x;
    int b = be >> 10;
    int tid = threadIdx.x, d2 = tid & 63, h = tid >> 6;
    __shared__ u16 sidx[CAP];
    __shared__ float2 part2[256];
    int cnt = rcnt[be];
    for (int i = tid; i < cnt; i += 256) sidx[i] = ridx[(size_t)be * CAP + i];
    __syncthreads();
    const float2* nb2 = (const float2*)(nodes + (size_t)b * N_ * H_);
    float2 acc = make_float2(0.f, 0.f);
    for (int i = h; i < cnt; i += 4) {
        float2 v = nb2[(size_t)sidx[i] * 64 + d2];
        acc.x += v.x; acc.y += v.y;
    }
    part2[tid] = acc;
    __syncthreads();
    if (tid < 64) {
        float2 a = part2[tid], bb = part2[tid + 64], cc = part2[tid + 128], dd = part2[tid + 192];
        float inv = 1.0f / (float)(cnt > 0 ? cnt : 1);
        float2 r;
        r.x = (a.x + bb.x + cc.x + dd.x) * inv;
        r.y = (a.y + bb.y + cc.y + dd.y) * inv;
        ((float2*)edge)[(size_t)be * 64 + tid] = r;
    }
}

// Masked-softmax attention over a nonzero list (float2-vectorized).
//   q = qsrc[row]*w[:H]; score_j = leaky_relu(dot(q, kv[lst[j]]) + w[H])
//   out[row] = sum_j softmax(score)_j * kv[lst[j]]
// Safe for qsrc == out (block only touches its own row).
// XCD swizzle: dispatch-order block x -> (batch, row) so batch b sits on XCD b%8.
__global__ void attn_gather(const float* __restrict__ qsrc,
                            const float* __restrict__ kv,
                            const float* __restrict__ w,
                            const u16* __restrict__ lidx, const int* __restrict__ lcnt,
                            float* __restrict__ out) {
    int x = blockIdx.x;
    int xcd = x & 7;
    int j = x >> 3;                      // 0..2047
    int b = xcd + ((j >> 10) << 3);      // batches {xcd, xcd+8}
    int r = j & 1023;
    int br = (b << 10) + r;
    int tid = threadIdx.x, lane = tid & 63, wv = tid >> 6;   // 256 threads
    __shared__ float q[H_];
    __shared__ u16 sidx[CAP];
    __shared__ float sc[CAP];
    __shared__ float rtmp[4];
    __shared__ float2 part2[256];
    int cnt = lcnt[br];
    for (int i = tid; i < cnt; i += 256) sidx[i] = lidx[(size_t)br * CAP + i];
    if (tid < H_) q[tid] = qsrc[(size_t)br * H_ + tid] * w[tid];
    __syncthreads();
    float wb = w[H_];
    const float2* kvb2 = (const float2*)(kv + (size_t)b * 1024 * H_);
    const float2* q2 = (const float2*)q;
    // scores: one wave per list entry, 8B/lane
    for (int i = wv; i < cnt; i += 4) {
        const float2* k2 = kvb2 + (size_t)sidx[i] * 64;
        float2 qq = q2[lane], kk = k2[lane];
        float p = qq.x * kk.x + qq.y * kk.y;
        p = wave_sum64(p);
        if (lane == 0) {
            p += wb;
            sc[i] = p >= 0.f ? p : 0.2f * p;   // LeakyReLU(0.2)
        }
    }
    __syncthreads();
    // softmax over sc[0..cnt)
    float v = (tid < cnt) ? sc[tid] : -1e30f;
    v = wave_max64(v);
    if (lane == 0) rtmp[wv] = v;
    __syncthreads();
    float m = fmaxf(fmaxf(rtmp[0], rtmp[1]), fmaxf(rtmp[2], rtmp[3]));
    float ee = (tid < cnt) ? __expf(sc[tid] - m) : 0.f;
    float s = wave_sum64(ee);
    __syncthreads();                 // rtmp(max) reads done before reuse
    if (lane == 0) rtmp[wv] = s;
    if (tid < cnt) sc[tid] = ee;
    __syncthreads();
    float denom = rtmp[0] + rtmp[1] + rtmp[2] + rtmp[3];
    float rden = denom > 0.f ? 1.0f / denom : 0.f;
    // aggregate: 4 list-slices, float2 per lane
    int d2 = tid & 63, h = tid >> 6;
    float2 acc = make_float2(0.f, 0.f);
    for (int i = h; i < cnt; i += 4) {
        float2 vv = kvb2[(size_t)sidx[i] * 64 + d2];
        float sw = sc[i];
        acc.x += sw * vv.x; acc.y += sw * vv.y;
    }
    part2[tid] = acc;
    __syncthreads();
    if (tid < 64) {
        float2 a = part2[tid], bb = part2[tid + 64], cc = part2[tid + 128], dd = part2[tid + 192];
        float2 rr;
        rr.x = (a.x + bb.x + cc.x + dd.x) * rden;
        rr.y = (a.y + bb.y + cc.y + dd.y) * rden;
        ((float2*)out)[(size_t)br * 64 + tid] = rr;
    }
}

extern "C" void kernel_launch(void* const* d_in, const int* in_sizes, int n_in,
                              void* d_out, int out_size, void* d_ws, size_t ws_size,
                              hipStream_t stream) {
    const float* nodes_in = (const float*)d_in[0];   // (B,N,H) f32
    const float* adj      = (const float*)d_in[1];   // (B,E,N) f32, binary
    const float* w1       = (const float*)d_in[2];   // (H+1)
    const float* w2       = (const float*)d_in[3];   // (H+1)

    char* ws = (char*)d_ws;
    size_t off = 0;
    u16* row_idx = (u16*)(ws + off); off += (size_t)B_ * E_ * CAP * sizeof(u16);
    u16* col_idx = (u16*)(ws + off); off += (size_t)B_ * N_ * CAP * sizeof(u16);
    int* row_cnt = (int*)(ws + off); off += (size_t)B_ * E_ * sizeof(int);
    int* col_cnt = (int*)(ws + off); off += (size_t)B_ * N_ * sizeof(int);
    int* cnt_chunk = (int*)(ws + off); off += (size_t)B_ * NC * N_ * sizeof(int);
    int* off_chunk = (int*)(ws + off); off += (size_t)B_ * NC * N_ * sizeof(int);

    float* out_nodes = (float*)d_out;                       // (B,N,H)
    float* out_edge  = out_nodes + (size_t)B_ * N_ * H_;    // (B,E,H)

    build_rows<<<dim3(B_ * E_), dim3(256), 0, stream>>>(adj, row_idx, row_cnt);
    col_count <<<dim3(B_ * NC * 4), dim3(256), 0, stream>>>(adj, cnt_chunk);
    col_prefix<<<dim3(B_ * N_ / 256), dim3(256), 0, stream>>>(cnt_chunk, off_chunk, col_cnt);
    col_place <<<dim3(B_ * NC * 4), dim3(256), 0, stream>>>(adj, off_chunk, col_idx);
    edge_init <<<dim3(B_ * E_), dim3(256), 0, stream>>>(nodes_in, row_idx, row_cnt, out_edge);

    const float* ncur = nodes_in;
    for (int s = 0; s < 2; ++s) {
        attn_gather<<<dim3(B_ * E_), dim3(256), 0, stream>>>(
            out_edge, ncur, w1, row_idx, row_cnt, out_edge);
        attn_gather<<<dim3(B_ * N_), dim3(256), 0, stream>>>(
            ncur, out_edge, w2, col_idx, col_cnt, out_nodes);
        ncur = out_nodes;
    }
}

// Round 3
// 366.381 us; speedup vs baseline: 3.2180x; 2.1470x over previous
//
#include <hip/hip_runtime.h>
#include <cstdint>
#include <cstddef>

#define B_ 16
#define E_ 1024
#define N_ 1024
#define H_ 128
#define CAP 256   // max nonzeros per row/col; Bernoulli(0.1,1024): mean 102, std 9.6
#define NC 16     // e-chunks for column build
#define EC 64     // E_/NC

typedef unsigned short u16;

__device__ __forceinline__ float wave_sum64(float v) {
    v += __shfl_xor(v, 32);
    v += __shfl_xor(v, 16);
    v += __shfl_xor(v, 8);
    v += __shfl_xor(v, 4);
    v += __shfl_xor(v, 2);
    v += __shfl_xor(v, 1);
    return v;
}

__device__ __forceinline__ float wave_max64(float v) {
    v = fmaxf(v, __shfl_xor(v, 32));
    v = fmaxf(v, __shfl_xor(v, 16));
    v = fmaxf(v, __shfl_xor(v, 8));
    v = fmaxf(v, __shfl_xor(v, 4));
    v = fmaxf(v, __shfl_xor(v, 2));
    v = fmaxf(v, __shfl_xor(v, 1));
    return v;
}

// Row nonzero lists: one block per (b,e). Coalesced, ordered (ascending n).
__global__ void build_rows(const float* __restrict__ adj,
                           u16* __restrict__ idx, int* __restrict__ cnt_out) {
    int be = blockIdx.x;                      // b*E + e
    const float* row = adj + (size_t)be * N_;
    __shared__ int wcnt[4];
    __shared__ int base;
    int tid = threadIdx.x, lane = tid & 63, wv = tid >> 6;
    if (tid == 0) base = 0;
    __syncthreads();
    for (int c0 = 0; c0 < N_; c0 += 256) {
        float v = row[c0 + tid];
        unsigned long long m = __ballot(v != 0.0f);
        if (lane == 0) wcnt[wv] = __popcll(m);
        __syncthreads();
        int pos = base;
        for (int w = 0; w < wv; ++w) pos += wcnt[w];
        pos += __popcll(m & ((1ull << lane) - 1ull));
        if (v != 0.0f && pos < CAP)
            idx[(size_t)be * CAP + pos] = (u16)(c0 + tid);
        __syncthreads();
        if (tid == 0) base += wcnt[0] + wcnt[1] + wcnt[2] + wcnt[3];
        __syncthreads();
    }
    if (tid == 0) cnt_out[be] = base < CAP ? base : CAP;
}

// --- Column lists, 3-phase parallel, deterministic (ascending e) ---
__global__ void col_count(const float* __restrict__ adj, int* __restrict__ cnt_chunk) {
    int blk = blockIdx.x;
    int ng = blk & 3;                 // n-group
    int c  = (blk >> 2) & (NC - 1);   // e-chunk
    int b  = blk >> 6;
    int n = (ng << 8) + threadIdx.x;
    const float* base = adj + ((size_t)(b * E_ + c * EC)) * N_ + n;
    int cc = 0;
#pragma unroll 8
    for (int e = 0; e < EC; ++e)
        cc += (base[(size_t)e * N_] != 0.0f);
    cnt_chunk[(size_t)(b * NC + c) * N_ + n] = cc;
}

__global__ void col_prefix(const int* __restrict__ cnt_chunk,
                           int* __restrict__ off_chunk, int* __restrict__ cnt_out) {
    int idx = blockIdx.x * 256 + threadIdx.x;   // b*N + n
    int b = idx >> 10, n = idx & 1023;
    int run = 0;
    for (int c = 0; c < NC; ++c) {
        size_t p = (size_t)(b * NC + c) * N_ + n;
        off_chunk[p] = run;
        run += cnt_chunk[p];
    }
    cnt_out[idx] = run < CAP ? run : CAP;
}

__global__ void col_place(const float* __restrict__ adj,
                          const int* __restrict__ off_chunk, u16* __restrict__ idx) {
    int blk = blockIdx.x;
    int ng = blk & 3;
    int c  = (blk >> 2) & (NC - 1);
    int b  = blk >> 6;
    int n = (ng << 8) + threadIdx.x;
    const float* base = adj + ((size_t)(b * E_ + c * EC)) * N_ + n;
    int pos = off_chunk[(size_t)(b * NC + c) * N_ + n];
    u16* lst = idx + ((size_t)b * N_ + n) * CAP;
    for (int e = 0; e < EC; ++e) {
        if (base[(size_t)e * N_] != 0.0f) {
            if (pos < CAP) lst[pos] = (u16)(c * EC + e);
            ++pos;
        }
    }
}

// edge_init[b,e,:] = mean of incident node rows. 256 thr, float4, 8 slices.
__global__ void edge_init(const float* __restrict__ nodes,
                          const u16* __restrict__ ridx, const int* __restrict__ rcnt,
                          float* __restrict__ edge) {
    int be = blockIdx.x;
    int b = be >> 10;
    int tid = threadIdx.x, d4 = tid & 31, h = tid >> 5;
    __shared__ u16 sidx[CAP];
    __shared__ float4 part4[256];
    int cnt = rcnt[be];
    for (int i = tid; i < cnt; i += 256) sidx[i] = ridx[(size_t)be * CAP + i];
    __syncthreads();
    const float4* nb4 = (const float4*)(nodes + (size_t)b * N_ * H_);
    float4 acc = make_float4(0.f, 0.f, 0.f, 0.f);
    for (int i = h; i < cnt; i += 8) {
        float4 v = nb4[(size_t)sidx[i] * 32 + d4];
        acc.x += v.x; acc.y += v.y; acc.z += v.z; acc.w += v.w;
    }
    part4[tid] = acc;
    __syncthreads();
    if (tid < 32) {
        float4 r = make_float4(0.f, 0.f, 0.f, 0.f);
#pragma unroll
        for (int k = 0; k < 8; ++k) {
            float4 p = part4[tid + (k << 5)];
            r.x += p.x; r.y += p.y; r.z += p.z; r.w += p.w;
        }
        float inv = 1.0f / (float)(cnt > 0 ? cnt : 1);
        r.x *= inv; r.y *= inv; r.z *= inv; r.w *= inv;
        ((float4*)edge)[(size_t)be * 32 + tid] = r;
    }
}

// Masked-softmax attention over a nonzero list.
// Score phase: 8 lanes per entry (in-register partial dots, 3-level shfl).
// Aggregate phase: float4, 8 list-slices.
// Safe for qsrc == out (block only touches its own row).
// XCD swizzle: batch b sits on XCD b%8 so per-XCD kv footprint is 2 batches (1 MB, L2-resident).
__global__ void attn_gather(const float* __restrict__ qsrc,
                            const float* __restrict__ kv,
                            const float* __restrict__ w,
                            const u16* __restrict__ lidx, const int* __restrict__ lcnt,
                            float* __restrict__ out) {
    int x = blockIdx.x;
    int xcd = x & 7;
    int j = x >> 3;                      // 0..2047
    int b = xcd + ((j >> 10) << 3);      // batches {xcd, xcd+8}
    int r = j & 1023;
    int br = (b << 10) + r;
    int tid = threadIdx.x, lane = tid & 63, wv = tid >> 6;   // 256 threads
    __shared__ float4 q4[32];            // q*w, 128 floats
    __shared__ u16 sidx[CAP];
    __shared__ float sc[CAP];
    __shared__ float rtmp[4];
    __shared__ float4 part4[256];
    int cnt = lcnt[br];
    for (int i = tid; i < cnt; i += 256) sidx[i] = lidx[(size_t)br * CAP + i];
    if (tid < H_) ((float*)q4)[tid] = qsrc[(size_t)br * H_ + tid] * w[tid];
    __syncthreads();
    float wb = w[H_];
    const float* kvb = kv + (size_t)b * 1024 * H_;

    // --- scores: 8 lanes/entry, 32 entries per 256-thread round ---
    int esub = lane >> 3;                // 0..7 entry within wave
    int dsub = lane & 7;                 // 0..7 d-subrange (16 floats each)
    for (int i0 = 0; i0 < cnt; i0 += 32) {
        int i = i0 + (wv << 3) + esub;
        int row = (i < cnt) ? sidx[i] : 0;
        const float4* kr = (const float4*)(kvb + (size_t)row * H_);
        float acc = 0.f;
#pragma unroll
        for (int jj = 0; jj < 4; ++jj) {
            float4 k4 = kr[(jj << 3) + dsub];
            float4 qq = q4[(jj << 3) + dsub];
            acc = fmaf(k4.x, qq.x, acc);
            acc = fmaf(k4.y, qq.y, acc);
            acc = fmaf(k4.z, qq.z, acc);
            acc = fmaf(k4.w, qq.w, acc);
        }
        acc += __shfl_xor(acc, 1);
        acc += __shfl_xor(acc, 2);
        acc += __shfl_xor(acc, 4);
        if (dsub == 0 && i < cnt) {
            float p = acc + wb;
            sc[i] = p >= 0.f ? p : 0.2f * p;   // LeakyReLU(0.2)
        }
    }
    __syncthreads();

    // --- softmax over sc[0..cnt) ---
    float v = (tid < cnt) ? sc[tid] : -1e30f;
    v = wave_max64(v);
    if (lane == 0) rtmp[wv] = v;
    __syncthreads();
    float m = fmaxf(fmaxf(rtmp[0], rtmp[1]), fmaxf(rtmp[2], rtmp[3]));
    float ee = (tid < cnt) ? __expf(sc[tid] - m) : 0.f;
    float s = wave_sum64(ee);
    __syncthreads();                 // rtmp(max) reads done before reuse
    if (lane == 0) rtmp[wv] = s;
    if (tid < cnt) sc[tid] = ee;
    __syncthreads();
    float denom = rtmp[0] + rtmp[1] + rtmp[2] + rtmp[3];
    float rden = denom > 0.f ? 1.0f / denom : 0.f;

    // --- aggregate: 8 list-slices, float4 per lane ---
    int d4 = tid & 31, h = tid >> 5;
    const float4* kvb4 = (const float4*)kvb;
    float4 acc4 = make_float4(0.f, 0.f, 0.f, 0.f);
    for (int i = h; i < cnt; i += 8) {
        float4 vv = kvb4[(size_t)sidx[i] * 32 + d4];
        float sw = sc[i];
        acc4.x = fmaf(sw, vv.x, acc4.x);
        acc4.y = fmaf(sw, vv.y, acc4.y);
        acc4.z = fmaf(sw, vv.z, acc4.z);
        acc4.w = fmaf(sw, vv.w, acc4.w);
    }
    part4[tid] = acc4;
    __syncthreads();
    if (tid < 32) {
        float4 rr = make_float4(0.f, 0.f, 0.f, 0.f);
#pragma unroll
        for (int k = 0; k < 8; ++k) {
            float4 p = part4[tid + (k << 5)];
            rr.x += p.x; rr.y += p.y; rr.z += p.z; rr.w += p.w;
        }
        rr.x *= rden; rr.y *= rden; rr.z *= rden; rr.w *= rden;
        ((float4*)out)[(size_t)br * 32 + tid] = rr;
    }
}

extern "C" void kernel_launch(void* const* d_in, const int* in_sizes, int n_in,
                              void* d_out, int out_size, void* d_ws, size_t ws_size,
                              hipStream_t stream) {
    const float* nodes_in = (const float*)d_in[0];   // (B,N,H) f32
    const float* adj      = (const float*)d_in[1];   // (B,E,N) f32, binary
    const float* w1       = (const float*)d_in[2];   // (H+1)
    const float* w2       = (const float*)d_in[3];   // (H+1)

    char* ws = (char*)d_ws;
    size_t off = 0;
    u16* row_idx = (u16*)(ws + off); off += (size_t)B_ * E_ * CAP * sizeof(u16);
    u16* col_idx = (u16*)(ws + off); off += (size_t)B_ * N_ * CAP * sizeof(u16);
    int* row_cnt = (int*)(ws + off); off += (size_t)B_ * E_ * sizeof(int);
    int* col_cnt = (int*)(ws + off); off += (size_t)B_ * N_ * sizeof(int);
    int* cnt_chunk = (int*)(ws + off); off += (size_t)B_ * NC * N_ * sizeof(int);
    int* off_chunk = (int*)(ws + off); off += (size_t)B_ * NC * N_ * sizeof(int);

    float* out_nodes = (float*)d_out;                       // (B,N,H)
    float* out_edge  = out_nodes + (size_t)B_ * N_ * H_;    // (B,E,H)

    build_rows<<<dim3(B_ * E_), dim3(256), 0, stream>>>(adj, row_idx, row_cnt);
    col_count <<<dim3(B_ * NC * 4), dim3(256), 0, stream>>>(adj, cnt_chunk);
    col_prefix<<<dim3(B_ * N_ / 256), dim3(256), 0, stream>>>(cnt_chunk, off_chunk, col_cnt);
    col_place <<<dim3(B_ * NC * 4), dim3(256), 0, stream>>>(adj, off_chunk, col_idx);
    edge_init <<<dim3(B_ * E_), dim3(256), 0, stream>>>(nodes_in, row_idx, row_cnt, out_edge);

    const float* ncur = nodes_in;
    for (int s = 0; s < 2; ++s) {
        attn_gather<<<dim3(B_ * E_), dim3(256), 0, stream>>>(
            out_edge, ncur, w1, row_idx, row_cnt, out_edge);
        attn_gather<<<dim3(B_ * N_), dim3(256), 0, stream>>>(
            ncur, out_edge, w2, col_idx, col_cnt, out_nodes);
        ncur = out_nodes;
    }
}